// Round 3
// baseline (468.043 us; speedup 1.0000x reference)
//
#include <hip/hip_runtime.h>

#define BB 64
#define PP 8732
#define OO 32
#define CC 81
#define NEGPOS 3
#define NCHUNK ((BB * PP) / 128)   // 4366 ce blocks

// ---------------- workspace layout (no initialization required) ----------------
// every element is written before it is read -> poison-proof
#define WS_LAB    0                         // int  lab[B*P]
#define WS_CENEG  (WS_LAB   + BB*PP*4)      // float ce_neg[B*P]
#define WS_CEPOS  (WS_CENEG + BB*PP*4)      // float cepos[NCHUNK]
#define WS_LSUMB  (WS_CEPOS + NCHUNK*4)     // float lsum_b[B]
#define WS_HARDB  (WS_LSUMB + BB*4)         // float hard_b[B]
#define WS_NPOSB  (WS_HARDB + BB*4)         // int  npos_b[B]

// ---------------- kernel 1: fused match (IoU + argmaxes + overrides + labels + loc loss)
// grid B, block 512. All per-batch state lives in LDS; no atomics, no global scratch.
__global__ __launch_bounds__(512) void match_kernel(
    const float* __restrict__ pred_locs, const float* __restrict__ boxes,
    const int* __restrict__ labels, const float* __restrict__ priors,
    int* __restrict__ lab_out, int* __restrict__ npos_b,
    float* __restrict__ lsum_b)
{
    const int b = blockIdx.x, tid = threadIdx.x;
    const int wid = tid >> 6, lane = tid & 63;

    __shared__ float sbx[OO * 4];                 // boxes (xy) for this batch
    __shared__ int   slab[OO];
    __shared__ unsigned long long sob[OO * 8];    // per-wave per-object bests
    __shared__ int   spfo[OO];                    // prior_for_object
    __shared__ float sbv[PP];                     // per-prior best iou
    __shared__ unsigned char sbo[PP];             // per-prior best obj
    __shared__ float sred[8];
    __shared__ int   sredi[8];

    if (tid < OO * 4) sbx[tid] = boxes[b * OO * 4 + tid];
    if (tid < OO)     slab[tid] = labels[b * OO + tid];
    __syncthreads();

    unsigned long long obest[OO];
#pragma unroll
    for (int o = 0; o < OO; ++o) obest[o] = 0ull;

    for (int p = tid; p < PP; p += 512) {
        float4 pr = ((const float4*)priors)[p];
        float plx = pr.x - pr.z * 0.5f, ply = pr.y - pr.w * 0.5f;
        float phx = pr.x + pr.z * 0.5f, phy = pr.y + pr.w * 0.5f;
        float parea = pr.z * pr.w;
        float bestv = -1.0f; int besto = 0;
#pragma unroll
        for (int o = 0; o < OO; ++o) {
            float b0 = sbx[o*4+0], b1 = sbx[o*4+1], b2 = sbx[o*4+2], b3 = sbx[o*4+3];
            float lox = fmaxf(b0, plx), loy = fmaxf(b1, ply);
            float hix = fminf(b2, phx), hiy = fminf(b3, phy);
            float inter = fmaxf(hix - lox, 0.0f) * fmaxf(hiy - loy, 0.0f);
            float iou = inter / ((b2 - b0) * (b3 - b1) + parea - inter);
            if (iou > bestv) { bestv = iou; besto = o; }  // strict > : first-max (np.argmax axis=0)
            unsigned long long enc =
                ((unsigned long long)__float_as_uint(iou) << 32) | (unsigned)(~(unsigned)p);
            obest[o] = (enc > obest[o]) ? enc : obest[o];  // max iou, tie -> min p
        }
        sbv[p] = bestv;
        sbo[p] = (unsigned char)besto;
    }

    // per-object argmax: wave shuffle-reduce, then 8 wave-partials in LDS
#pragma unroll
    for (int o = 0; o < OO; ++o) {
        unsigned long long v = obest[o];
        for (int off = 32; off > 0; off >>= 1) {
            unsigned long long w = __shfl_down(v, off, 64);
            v = (w > v) ? w : v;
        }
        if (lane == 0) sob[o * 8 + wid] = v;
    }
    __syncthreads();
    if (tid < OO) {
        unsigned long long m = 0ull;
#pragma unroll
        for (int w = 0; w < 8; ++w) {
            unsigned long long v = sob[tid * 8 + w];
            m = (v > m) ? v : m;
        }
        spfo[tid] = (int)(~(unsigned)(m & 0xFFFFFFFFull));
    }
    __syncthreads();

    // phase 2: forced positives (ascending oo => last-write-wins, numpy scatter), labels, loc loss
    float lsum = 0.0f; int lpos = 0;
    for (int p = tid; p < PP; p += 512) {
        int o = sbo[p];
        float ov = sbv[p];
#pragma unroll
        for (int oo = 0; oo < OO; ++oo)
            if (spfo[oo] == p) { o = oo; ov = 1.0f; }
        int l = (ov < 0.5f) ? 0 : slab[o];
        lab_out[b * PP + p] = l;
        if (l != 0) {
            lpos++;
            float b0 = sbx[o*4+0], b1 = sbx[o*4+1], b2 = sbx[o*4+2], b3 = sbx[o*4+3];
            float4 pr = ((const float4*)priors)[p];
            float gx = ((b0 + b2) * 0.5f - pr.x) / (pr.z * 0.1f);
            float gy = ((b1 + b3) * 0.5f - pr.y) / (pr.w * 0.1f);
            float gw = logf((b2 - b0) / pr.z) * 5.0f;
            float gh = logf((b3 - b1) / pr.w) * 5.0f;
            float4 pl = ((const float4*)pred_locs)[b * PP + p];
            lsum += fabsf(pl.x - gx) + fabsf(pl.y - gy) + fabsf(pl.z - gw) + fabsf(pl.w - gh);
        }
    }
    for (int off = 32; off > 0; off >>= 1) {
        lsum += __shfl_down(lsum, off, 64);
        lpos += __shfl_down(lpos, off, 64);
    }
    if (lane == 0) { sred[wid] = lsum; sredi[wid] = lpos; }
    __syncthreads();
    if (tid == 0) {
        float s = 0.0f; int n = 0;
#pragma unroll
        for (int w = 0; w < 8; ++w) { s += sred[w]; n += sredi[w]; }
        lsum_b[b] = s;
        npos_b[b] = n;
    }
}

// ---------------- kernel 2: cross entropy ----------------
// grid NCHUNK=4366, block 128. float4 LDS staging, fully coalesced. No atomics.
__global__ __launch_bounds__(128) void ce_kernel(
    const float* __restrict__ scores, const int* __restrict__ lab,
    float* __restrict__ ce_neg, float* __restrict__ cepos)
{
    __shared__ float ss[128 * CC];   // 41472 B
    const int tid = threadIdx.x;
    const int bp = blockIdx.x * 128 + tid;
    const int l = lab[bp];           // issue early, overlaps staging

    const float4* __restrict__ src =
        (const float4*)(scores + (long long)blockIdx.x * (128 * CC));
    float4* dst = (float4*)ss;
#pragma unroll 4
    for (int i = tid; i < (128 * CC) / 4; i += 128) dst[i] = src[i];
    __syncthreads();

    const float* v = ss + tid * CC;   // stride 81: odd -> 2-way bank aliasing (free)
    float m = v[0];
#pragma unroll
    for (int c = 1; c < CC; ++c) m = fmaxf(m, v[c]);
    float sum = 0.0f;
#pragma unroll
    for (int c = 0; c < CC; ++c) sum += __expf(v[c] - m);
    float lse = m + __logf(sum);
    float ce = lse - v[l];
    float pos = (l != 0) ? ce : 0.0f;
    ce_neg[bp] = (l != 0) ? 0.0f : ce;

    for (int off = 32; off > 0; off >>= 1) pos += __shfl_down(pos, off, 64);
    __shared__ float sr[2];
    if ((tid & 63) == 0) sr[tid >> 6] = pos;
    __syncthreads();
    if (tid == 0) cepos[blockIdx.x] = sr[0] + sr[1];
}

// ---------------- kernel 3: per-batch exact top-K sum via radix select ----------------
// grid B, block 256. 16-slot bank-split histogram + parallel compaction.
__global__ __launch_bounds__(256) void topk_kernel(
    const float* __restrict__ ce_neg, const int* __restrict__ npos_b,
    float* __restrict__ hard_b)
{
    __shared__ float sv[PP];          // 34928 B
    __shared__ int hist[256 * 16];    // 16-way slot-split histogram (16 KB)
    __shared__ int chist[256];        // compacted
    __shared__ unsigned sel[2];
    __shared__ float sr[4];
    const int b = blockIdx.x, tid = threadIdx.x;
    for (int p = tid; p < PP; p += 256) sv[p] = ce_neg[b * PP + p];
    int K = NEGPOS * npos_b[b];
    if (K > PP) K = PP;
    __syncthreads();

    float hard = 0.0f;
    if (K > 0) {
        unsigned prefix = 0, mask = 0;
        unsigned remaining = (unsigned)K;
        for (int pass = 0; pass < 4; ++pass) {
            const int shift = 24 - 8 * pass;
            for (int i = tid; i < 256 * 16; i += 256) hist[i] = 0;
            __syncthreads();
            for (int p = tid; p < PP; p += 256) {
                unsigned u = __float_as_uint(sv[p]);   // all ce >= 0: bits monotone
                if ((u & mask) == prefix)
                    atomicAdd(&hist[(((u >> shift) & 255) << 4) | (tid & 15)], 1);
            }
            __syncthreads();
            {   // parallel slot compaction: thread i owns bin i
                int s = 0;
#pragma unroll
                for (int w = 0; w < 16; ++w) s += hist[(tid << 4) | w];
                chist[tid] = s;
            }
            __syncthreads();
            if (tid == 0) {
                unsigned cum = 0; int binsel = 0;
                for (int i = 255; i >= 0; --i) {
                    unsigned h = (unsigned)chist[i];
                    if (cum + h >= remaining) { binsel = i; break; }
                    cum += h;
                }
                sel[0] = (unsigned)binsel;
                sel[1] = remaining - cum;
            }
            __syncthreads();
            prefix |= sel[0] << shift;
            mask |= 0xFFu << shift;
            remaining = sel[1];
            __syncthreads();
        }
        // prefix = bits of K-th largest; remaining = # cutoff-valued elems inside top-K
        float sgt = 0.0f;
        for (int p = tid; p < PP; p += 256) {
            unsigned u = __float_as_uint(sv[p]);
            if (u > prefix) sgt += sv[p];
        }
        for (int off = 32; off > 0; off >>= 1) sgt += __shfl_down(sgt, off, 64);
        if ((tid & 63) == 0) sr[tid >> 6] = sgt;
        __syncthreads();
        if (tid == 0)
            hard = sr[0] + sr[1] + sr[2] + sr[3]
                 + __uint_as_float(prefix) * (float)remaining;
    }
    if (tid == 0) hard_b[b] = hard;
}

// ---------------- kernel 4: finalize ----------------
// 1 block, 256 threads: sum the small partial arrays, write the scalar loss.
__global__ __launch_bounds__(256) void finalize_kernel(
    const float* __restrict__ cepos, const float* __restrict__ lsum_b,
    const float* __restrict__ hard_b, const int* __restrict__ npos_b,
    float* __restrict__ out)
{
    const int tid = threadIdx.x;
    float cpos = 0.0f;
    for (int i = tid; i < NCHUNK; i += 256) cpos += cepos[i];
    float labs = 0.0f, chard = 0.0f; int n = 0;
    if (tid < BB) { labs = lsum_b[tid]; chard = hard_b[tid]; n = npos_b[tid]; }
    for (int off = 32; off > 0; off >>= 1) {
        cpos  += __shfl_down(cpos, off, 64);
        labs  += __shfl_down(labs, off, 64);
        chard += __shfl_down(chard, off, 64);
        n     += __shfl_down(n, off, 64);
    }
    __shared__ float s0[4], s1[4], s2[4];
    __shared__ int s3[4];
    if ((tid & 63) == 0) { int w = tid >> 6; s0[w] = cpos; s1[w] = labs; s2[w] = chard; s3[w] = n; }
    __syncthreads();
    if (tid == 0) {
        float a = s0[0]+s0[1]+s0[2]+s0[3];
        float bsum = s1[0]+s1[1]+s1[2]+s1[3];
        float c = s2[0]+s2[1]+s2[2]+s2[3];
        float nf = (float)(s3[0]+s3[1]+s3[2]+s3[3]);
        out[0] = (c + a) / nf + bsum / (nf * 4.0f);
    }
}

extern "C" void kernel_launch(void* const* d_in, const int* in_sizes, int n_in,
                              void* d_out, int out_size, void* d_ws, size_t ws_size,
                              hipStream_t stream) {
    const float* pred_locs   = (const float*)d_in[0];   // [B,P,4]
    const float* pred_scores = (const float*)d_in[1];   // [B,P,C]
    const float* boxes       = (const float*)d_in[2];   // [B,O,4]
    const int*   labels      = (const int*)d_in[3];     // [B,O]
    const float* priors      = (const float*)d_in[4];   // [P,4] cxcywh
    float* out = (float*)d_out;

    char* ws = (char*)d_ws;
    int*   lab    = (int*)(ws + WS_LAB);
    float* ce_neg = (float*)(ws + WS_CENEG);
    float* cepos  = (float*)(ws + WS_CEPOS);
    float* lsum_b = (float*)(ws + WS_LSUMB);
    float* hard_b = (float*)(ws + WS_HARDB);
    int*   nposb  = (int*)(ws + WS_NPOSB);

    match_kernel<<<BB, 512, 0, stream>>>(pred_locs, boxes, labels, priors,
                                         lab, nposb, lsum_b);
    ce_kernel<<<NCHUNK, 128, 0, stream>>>(pred_scores, lab, ce_neg, cepos);
    topk_kernel<<<BB, 256, 0, stream>>>(ce_neg, nposb, hard_b);
    finalize_kernel<<<1, 256, 0, stream>>>(cepos, lsum_b, hard_b, nposb, out);
}

// Round 4
// 358.379 us; speedup vs baseline: 1.3060x; 1.3060x over previous
//
#include <hip/hip_runtime.h>

#define BB 64
#define PP 8732
#define OO 32
#define CC 81
#define NEGPOS 3
#define NCHUNK ((BB * PP) / 128)   // 4366 ce blocks
#define NSL_A 18                   // match_a: 18*512 = 9216 >= 8732
#define NCH_B 32                   // match_omax chunks: 32*273 = 8736 >= 8732
#define CHB 273
#define NSL_C 8                    // match_b slices: 8*1092 = 8736 >= 8732
#define SLC 1092

// ---------------- workspace layout (poison-proof: every word written before read) ----
#define WS_POVFP  0                              // u64 povfp[B*PP]  (iou_bits<<32 | obj)
#define WS_BESTP  (WS_POVFP + BB*PP*8)           // u64 bestp[B*NCH_B*OO]
#define WS_LAB    (WS_BESTP + BB*NCH_B*OO*8)     // int lab[B*PP]
#define WS_CENEG  (WS_LAB   + BB*PP*4)           // float ce_neg[B*P]
#define WS_CEPOS  (WS_CENEG + BB*PP*4)           // float cepos[NCHUNK]
#define WS_LSUMB  (WS_CEPOS + NCHUNK*4)          // float lsum_bs[B*NSL_C]
#define WS_NPOSB  (WS_LSUMB + BB*NSL_C*4)        // int   npos_bs[B*NSL_C]
#define WS_HARDB  (WS_NPOSB + BB*NSL_C*4)        // float hard_b[B]

// ---------------- kernel 1: per-prior best object ----------------
// grid (18,B) x 512: one prior per thread, running max in registers, no reduction.
__global__ __launch_bounds__(512) void match_a(
    const float* __restrict__ boxes, const float* __restrict__ priors,
    unsigned long long* __restrict__ povfp)
{
    const int b = blockIdx.y;
    __shared__ float sbx[OO * 4];
    if (threadIdx.x < OO * 4) sbx[threadIdx.x] = boxes[b * OO * 4 + threadIdx.x];
    __syncthreads();
    const int p = blockIdx.x * 512 + threadIdx.x;
    if (p >= PP) return;

    float4 pr = ((const float4*)priors)[p];
    float plx = pr.x - pr.z * 0.5f, ply = pr.y - pr.w * 0.5f;
    float phx = pr.x + pr.z * 0.5f, phy = pr.y + pr.w * 0.5f;
    float parea = pr.z * pr.w;
    float bestv = -1.0f; int besto = 0;
#pragma unroll
    for (int o = 0; o < OO; ++o) {
        float b0 = sbx[o*4+0], b1 = sbx[o*4+1], b2 = sbx[o*4+2], b3 = sbx[o*4+3];
        float lox = fmaxf(b0, plx), loy = fmaxf(b1, ply);
        float hix = fminf(b2, phx), hiy = fminf(b3, phy);
        float inter = fmaxf(hix - lox, 0.0f) * fmaxf(hiy - loy, 0.0f);
        float iou = inter / ((b2 - b0) * (b3 - b1) + parea - inter);
        if (iou > bestv) { bestv = iou; besto = o; }   // strict >: first-max (np.argmax axis=0)
    }
    povfp[b * PP + p] = ((unsigned long long)__float_as_uint(bestv) << 32) | (unsigned)besto;
}

// ---------------- kernel 2: per-object best prior ----------------
// grid (32,B) x 256: thread = (obj = tid&31, sub = tid>>5); running max in registers.
__global__ __launch_bounds__(256) void match_omax(
    const float* __restrict__ boxes, const float* __restrict__ priors,
    unsigned long long* __restrict__ bestp)
{
    const int b = blockIdx.y, ch = blockIdx.x, tid = threadIdx.x;
    const int o = tid & 31, sub = tid >> 5;           // sub 0..7
    const float b0 = boxes[(b*OO + o)*4 + 0], b1 = boxes[(b*OO + o)*4 + 1];
    const float b2 = boxes[(b*OO + o)*4 + 2], b3 = boxes[(b*OO + o)*4 + 3];
    const float barea = (b2 - b0) * (b3 - b1);
    const int base = ch * CHB;

    unsigned long long best = 0ull;
    for (int i = sub; i < CHB; i += 8) {
        int p = base + i;
        if (p >= PP) break;
        float4 pr = ((const float4*)priors)[p];
        float plx = pr.x - pr.z * 0.5f, ply = pr.y - pr.w * 0.5f;
        float phx = pr.x + pr.z * 0.5f, phy = pr.y + pr.w * 0.5f;
        float parea = pr.z * pr.w;
        float lox = fmaxf(b0, plx), loy = fmaxf(b1, ply);
        float hix = fminf(b2, phx), hiy = fminf(b3, phy);
        float inter = fmaxf(hix - lox, 0.0f) * fmaxf(hiy - loy, 0.0f);
        float iou = inter / (barea + parea - inter);
        unsigned long long enc =
            ((unsigned long long)__float_as_uint(iou) << 32) | (unsigned)(~(unsigned)p);
        best = (enc > best) ? enc : best;             // max iou, tie -> min p (np first-max)
    }
    // lanes l and l+32 share the same object
    unsigned long long w = __shfl_down(best, 32, 64);
    best = (w > best) ? w : best;
    __shared__ unsigned long long sred[4 * OO];
    if ((tid & 63) < 32) sred[(tid >> 6) * OO + o] = best;
    __syncthreads();
    if (tid < OO) {
        unsigned long long m = 0ull;
#pragma unroll
        for (int wv = 0; wv < 4; ++wv) {
            unsigned long long v = sred[wv * OO + tid];
            m = (v > m) ? v : m;
        }
        bestp[(b * NCH_B + ch) * OO + tid] = m;
    }
}

// ---------------- kernel 3: overrides + labels + loc loss ----------------
// grid (8,B) x 256. LDS override table instead of 32-way per-prior scan.
__global__ __launch_bounds__(256) void match_b(
    const float* __restrict__ pred_locs, const float* __restrict__ boxes,
    const int* __restrict__ labels, const float* __restrict__ priors,
    const unsigned long long* __restrict__ povfp,
    const unsigned long long* __restrict__ bestp,
    int* __restrict__ lab_out, int* __restrict__ npos_bs,
    float* __restrict__ lsum_bs)
{
    const int b = blockIdx.y, sl = blockIdx.x, tid = threadIdx.x;
    const int base = sl * SLC;
    __shared__ float sbx[OO * 4];
    __shared__ int   slab[OO];
    __shared__ int   spfo[OO];
    __shared__ signed char sovr[SLC];
    __shared__ float sredf[4];
    __shared__ int   sredi[4];

    if (tid < OO * 4) sbx[tid] = boxes[b * OO * 4 + tid];
    if (tid < OO)     slab[tid] = labels[b * OO + tid];
    if (tid < OO) {   // reduce the 32 chunk-partials for this object
        unsigned long long m = 0ull;
        for (int c = 0; c < NCH_B; ++c) {
            unsigned long long v = bestp[(b * NCH_B + c) * OO + tid];
            m = (v > m) ? v : m;
        }
        spfo[tid] = (int)(~(unsigned)(m & 0xFFFFFFFFull));
    }
    for (int i = tid; i < SLC; i += 256) sovr[i] = -1;
    __syncthreads();
    if (tid == 0) {   // ascending o => last-write-wins (numpy scatter semantics)
        for (int o = 0; o < OO; ++o) {
            int p = spfo[o] - base;
            if (p >= 0 && p < SLC) sovr[p] = (signed char)o;
        }
    }
    __syncthreads();

    float lsum = 0.0f; int lpos = 0;
    for (int i = tid; i < SLC; i += 256) {
        int p = base + i;
        if (p >= PP) break;
        unsigned long long pv = povfp[b * PP + p];
        int o = (int)(pv & 0xFFu);
        float ov = __uint_as_float((unsigned)(pv >> 32));
        int ovr = sovr[i];
        if (ovr >= 0) { o = ovr; ov = 1.0f; }
        int l = (ov < 0.5f) ? 0 : slab[o];
        lab_out[b * PP + p] = l;
        if (l != 0) {
            lpos++;
            float b0 = sbx[o*4+0], b1 = sbx[o*4+1], b2 = sbx[o*4+2], b3 = sbx[o*4+3];
            float4 pr = ((const float4*)priors)[p];
            float gx = ((b0 + b2) * 0.5f - pr.x) / (pr.z * 0.1f);
            float gy = ((b1 + b3) * 0.5f - pr.y) / (pr.w * 0.1f);
            float gw = logf((b2 - b0) / pr.z) * 5.0f;
            float gh = logf((b3 - b1) / pr.w) * 5.0f;
            float4 pl = ((const float4*)pred_locs)[b * PP + p];
            lsum += fabsf(pl.x - gx) + fabsf(pl.y - gy) + fabsf(pl.z - gw) + fabsf(pl.w - gh);
        }
    }
    for (int off = 32; off > 0; off >>= 1) {
        lsum += __shfl_down(lsum, off, 64);
        lpos += __shfl_down(lpos, off, 64);
    }
    if ((tid & 63) == 0) { sredf[tid >> 6] = lsum; sredi[tid >> 6] = lpos; }
    __syncthreads();
    if (tid == 0) {
        float s = 0.0f; int n = 0;
#pragma unroll
        for (int w = 0; w < 4; ++w) { s += sredf[w]; n += sredi[w]; }
        lsum_bs[b * NSL_C + sl] = s;
        npos_bs[b * NSL_C + sl] = n;
    }
}

// ---------------- kernel 4: cross entropy ----------------
// grid NCHUNK=4366, block 128. float4 LDS staging, fully coalesced. No atomics.
__global__ __launch_bounds__(128) void ce_kernel(
    const float* __restrict__ scores, const int* __restrict__ lab,
    float* __restrict__ ce_neg, float* __restrict__ cepos)
{
    __shared__ float ss[128 * CC];   // 41472 B
    const int tid = threadIdx.x;
    const int bp = blockIdx.x * 128 + tid;
    const int l = lab[bp];           // issue early, overlaps staging

    const float4* __restrict__ src =
        (const float4*)(scores + (long long)blockIdx.x * (128 * CC));
    float4* dst = (float4*)ss;
#pragma unroll 4
    for (int i = tid; i < (128 * CC) / 4; i += 128) dst[i] = src[i];
    __syncthreads();

    const float* v = ss + tid * CC;   // stride 81: odd -> 2-way bank aliasing (free)
    float m = v[0];
#pragma unroll
    for (int c = 1; c < CC; ++c) m = fmaxf(m, v[c]);
    float sum = 0.0f;
#pragma unroll
    for (int c = 0; c < CC; ++c) sum += __expf(v[c] - m);
    float lse = m + __logf(sum);
    float ce = lse - v[l];
    float pos = (l != 0) ? ce : 0.0f;
    ce_neg[bp] = (l != 0) ? 0.0f : ce;

    for (int off = 32; off > 0; off >>= 1) pos += __shfl_down(pos, off, 64);
    __shared__ float sr[2];
    if ((tid & 63) == 0) sr[tid >> 6] = pos;
    __syncthreads();
    if (tid == 0) cepos[blockIdx.x] = sr[0] + sr[1];
}

// ---------------- kernel 5: per-batch exact top-K sum via radix select ----------------
// grid B, block 512. 16-slot bank-split histogram + parallel compaction.
__global__ __launch_bounds__(512) void topk_kernel(
    const float* __restrict__ ce_neg, const int* __restrict__ npos_bs,
    float* __restrict__ hard_b)
{
    __shared__ float sv[PP];          // 34928 B
    __shared__ int hist[256 * 16];    // 16-way slot-split histogram (16 KB)
    __shared__ int chist[256];
    __shared__ unsigned sel[2];
    __shared__ float sr[8];
    __shared__ int sK;
    const int b = blockIdx.x, tid = threadIdx.x;
    for (int p = tid; p < PP; p += 512) sv[p] = ce_neg[b * PP + p];
    if (tid == 0) {
        int n = 0;
        for (int c = 0; c < NSL_C; ++c) n += npos_bs[b * NSL_C + c];
        int k = NEGPOS * n;
        sK = (k > PP) ? PP : k;
    }
    __syncthreads();
    const int K = sK;

    float hard = 0.0f;
    if (K > 0) {
        unsigned prefix = 0, mask = 0;
        unsigned remaining = (unsigned)K;
        for (int pass = 0; pass < 4; ++pass) {
            const int shift = 24 - 8 * pass;
            for (int i = tid; i < 256 * 16; i += 512) hist[i] = 0;
            __syncthreads();
            for (int p = tid; p < PP; p += 512) {
                unsigned u = __float_as_uint(sv[p]);   // all ce >= 0: bits monotone
                if ((u & mask) == prefix)
                    atomicAdd(&hist[(((u >> shift) & 255) << 4) | (tid & 15)], 1);
            }
            __syncthreads();
            if (tid < 256) {   // thread i compacts bin i
                int s = 0;
#pragma unroll
                for (int w = 0; w < 16; ++w) s += hist[(tid << 4) | w];
                chist[tid] = s;
            }
            __syncthreads();
            if (tid == 0) {
                unsigned cum = 0; int binsel = 0;
                for (int i = 255; i >= 0; --i) {
                    unsigned h = (unsigned)chist[i];
                    if (cum + h >= remaining) { binsel = i; break; }
                    cum += h;
                }
                sel[0] = (unsigned)binsel;
                sel[1] = remaining - cum;
            }
            __syncthreads();
            prefix |= sel[0] << shift;
            mask |= 0xFFu << shift;
            remaining = sel[1];
            __syncthreads();
        }
        // prefix = bits of K-th largest; remaining = # cutoff-valued elems inside top-K
        float sgt = 0.0f;
        for (int p = tid; p < PP; p += 512) {
            unsigned u = __float_as_uint(sv[p]);
            if (u > prefix) sgt += sv[p];
        }
        for (int off = 32; off > 0; off >>= 1) sgt += __shfl_down(sgt, off, 64);
        if ((tid & 63) == 0) sr[tid >> 6] = sgt;
        __syncthreads();
        if (tid == 0) {
            hard = 0.0f;
#pragma unroll
            for (int w = 0; w < 8; ++w) hard += sr[w];
            hard += __uint_as_float(prefix) * (float)remaining;
        }
    }
    if (tid == 0) hard_b[b] = hard;
}

// ---------------- kernel 6: finalize ----------------
__global__ __launch_bounds__(256) void finalize_kernel(
    const float* __restrict__ cepos, const float* __restrict__ lsum_bs,
    const float* __restrict__ hard_b, const int* __restrict__ npos_bs,
    float* __restrict__ out)
{
    const int tid = threadIdx.x;
    float cpos = 0.0f, labs = 0.0f, chard = 0.0f; int n = 0;
    for (int i = tid; i < NCHUNK; i += 256) cpos += cepos[i];
    for (int i = tid; i < BB * NSL_C; i += 256) { labs += lsum_bs[i]; n += npos_bs[i]; }
    if (tid < BB) chard = hard_b[tid];
    for (int off = 32; off > 0; off >>= 1) {
        cpos  += __shfl_down(cpos, off, 64);
        labs  += __shfl_down(labs, off, 64);
        chard += __shfl_down(chard, off, 64);
        n     += __shfl_down(n, off, 64);
    }
    __shared__ float s0[4], s1[4], s2[4];
    __shared__ int s3[4];
    if ((tid & 63) == 0) { int w = tid >> 6; s0[w] = cpos; s1[w] = labs; s2[w] = chard; s3[w] = n; }
    __syncthreads();
    if (tid == 0) {
        float a = s0[0]+s0[1]+s0[2]+s0[3];
        float bsum = s1[0]+s1[1]+s1[2]+s1[3];
        float c = s2[0]+s2[1]+s2[2]+s2[3];
        float nf = (float)(s3[0]+s3[1]+s3[2]+s3[3]);
        out[0] = (c + a) / nf + bsum / (nf * 4.0f);
    }
}

extern "C" void kernel_launch(void* const* d_in, const int* in_sizes, int n_in,
                              void* d_out, int out_size, void* d_ws, size_t ws_size,
                              hipStream_t stream) {
    const float* pred_locs   = (const float*)d_in[0];   // [B,P,4]
    const float* pred_scores = (const float*)d_in[1];   // [B,P,C]
    const float* boxes       = (const float*)d_in[2];   // [B,O,4]
    const int*   labels      = (const int*)d_in[3];     // [B,O]
    const float* priors      = (const float*)d_in[4];   // [P,4] cxcywh
    float* out = (float*)d_out;

    char* ws = (char*)d_ws;
    unsigned long long* povfp = (unsigned long long*)(ws + WS_POVFP);
    unsigned long long* bestp = (unsigned long long*)(ws + WS_BESTP);
    int*   lab     = (int*)(ws + WS_LAB);
    float* ce_neg  = (float*)(ws + WS_CENEG);
    float* cepos   = (float*)(ws + WS_CEPOS);
    float* lsum_bs = (float*)(ws + WS_LSUMB);
    int*   nposbs  = (int*)(ws + WS_NPOSB);
    float* hard_b  = (float*)(ws + WS_HARDB);

    match_a<<<dim3(NSL_A, BB), 512, 0, stream>>>(boxes, priors, povfp);
    match_omax<<<dim3(NCH_B, BB), 256, 0, stream>>>(boxes, priors, bestp);
    match_b<<<dim3(NSL_C, BB), 256, 0, stream>>>(pred_locs, boxes, labels, priors,
                                                 povfp, bestp, lab, nposbs, lsum_bs);
    ce_kernel<<<NCHUNK, 128, 0, stream>>>(pred_scores, lab, ce_neg, cepos);
    topk_kernel<<<BB, 512, 0, stream>>>(ce_neg, nposbs, hard_b);
    finalize_kernel<<<1, 256, 0, stream>>>(cepos, lsum_bs, hard_b, nposbs, out);
}